// Round 14
// baseline (8101.727 us; speedup 1.0000x reference)
//
#include <hip/hip_runtime.h>

// ScaledODENetFE: forward-Euler scan, T=44100, B=32, F=1, S=16, H=64.
// One wave per batch; lane k owns hidden unit k. ISSUE-COUNT bound
// (~1.1-1.2 ns per issued op; combine = half the per-step budget).
// R13 = R11 + ONE change: the r-combine's 16 scalar FMAs -> 8 v_pk_fma_f32
// on SGPR-broadcast pairs {Pb_2q, Pb_2q+1} (VOP3P takes one 64-bit scalar
// operand) with precomputed weight pairs; 2 chains x depth-4 + pk_add.
// Combine: 16 readlane + 16 fma + 3 add (34 slots) -> 16 readlane +
// 8 pk_fma/mul + 1 pk_add + 1 add (~26 slots).
// RETIRED: rotation combine (R9, R12 both regressed — DPP fusion does not
// fire as modeled). BANNED: permlane16/32_swap (R4/R5 wrong data), LDS
// P-broadcast on-chain (R7), carry reconstruction by cancellation (R10).

#define SRATE 44100.0f
#define T_TOTAL 44100
#define BATCH 32
#define HID 64
#define ST 16
#define KSCALE 2.8853900817779268f   // 2*log2(e)

typedef float v2f __attribute__((ext_vector_type(2)));

template <int CTRL>
__device__ __forceinline__ float dppmov(float x) {
    return __builtin_bit_cast(float,
        __builtin_amdgcn_update_dpp(0, __builtin_bit_cast(int, x),
                                    CTRL, 0xF, 0xF, false));
}

__device__ __forceinline__ float bcast(float v, int lane) {
    return __builtin_bit_cast(float,
        __builtin_amdgcn_readlane(__builtin_bit_cast(int, v), lane));
}

__device__ __forceinline__ int parity(int v) { return __builtin_popcount(v) & 1; }

__global__ __launch_bounds__(64, 1)
void ScaledODENetFE_kernel(const float* __restrict__ x,
                           const float* __restrict__ W1,
                           const float* __restrict__ b1,
                           const float* __restrict__ W2,
                           const float* __restrict__ b2v,
                           float* __restrict__ out) {
    const int b = blockIdx.x;      // batch element
    const int lane = threadIdx.x;  // hidden unit k
    const int TM1 = T_TOTAL - 1;   // 44099 scan steps

    // ---- one-time precompute (lane k) ----
    const float w1xK = W1[lane] * KSCALE;       // K-scaled x weight
    float w1yd[ST];                             // K * W1[1+s][lane] / sr
    #pragma unroll
    for (int s = 0; s < ST; ++s)
        w1yd[s] = (W1[(1 + s) * HID + lane] / SRATE) * KSCALE;

    // C2 = sum_s (b2[s] + pconst_s) * w1yd[s];  pconst_s = sum_k W2[k,s].
    float C2 = 0.f;
    #pragma unroll
    for (int s = 0; s < ST; ++s) C2 = fmaf(b2v[s], w1yd[s], C2);
    float pconst0 = 0.f;
    for (int s = 0; s < ST; ++s) {
        float pc = 0.f;
        for (int k = 0; k < HID; ++k) pc += W2[k * ST + s];
        C2 = fmaf(pc, w1yd[s], C2);
        if (s == 0) pconst0 = pc;
    }

    // Weight pairs for the packed combine: w1yd2[q] = {w1yd[2q], w1yd[2q+1]}.
    v2f w1yd2[8];
    #pragma unroll
    for (int qq = 0; qq < 8; ++qq)
        w1yd2[qq] = (v2f){w1yd[2 * qq], w1yd[2 * qq + 1]};

    // Dual-basis lane phis for the permuted W2 layout (XOR gens 1,2,7,8),
    // weights pre-scaled by -2 (r-form: p = pconst - 2 * W2^T r).
    const int p1 = parity(lane & 5), p2 = parity(lane & 6);
    const int p3 = (lane >> 2) & 1, p4 = (lane >> 3) & 1;
    float wA[8], wB[8];
    #pragma unroll
    for (int j = 0; j < 8; ++j) {
        const int i = 2 * j;
        const int c1 = (i & 1) ^ p1;
        const int c2 = ((i >> 1) & 1) ^ p2;
        const int c3 = ((i >> 2) & 1) ^ p3;
        const int c4 = ((i >> 3) & 1) ^ p4;
        const int s = (c1 ? 1 : 0) ^ (c2 ? 2 : 0) ^ (c3 ? 7 : 0) ^ (c4 ? 8 : 0);
        wA[j] = -2.f * W2[lane * ST + s];
        wB[j] = -2.f * W2[(lane ^ 1) * ST + s];
    }
    v2f wA2[4], wB2[4];
    #pragma unroll
    for (int m = 0; m < 4; ++m) {
        wA2[m] = (v2f){wA[2 * m], wA[2 * m + 1]};
        wB2[m] = (v2f){wB[2 * m], wB[2 * m + 1]};
    }

    const int bp32 = ((lane ^ 32) & 63) << 2;   // ds_bpermute byte addrs
    const int bp48 = ((lane ^ 48) & 63) << 2;
    const float b20 = b2v[0];

    float V  = b1[lane] * KSCALE;               // K-scaled carry (y starts 0)
    float y0 = 0.f;

    if (lane == 0) out[b] = 0.f;                // row t=0 is zeros

    // Lane l holds x[(t0+l)*B + b]; prefetch one chunk ahead.
    float xv = x[min(lane, TM1 - 1) * BATCH + b];
    float z = fmaf(bcast(xv, 0), w1xK, V);      // z_0 (K-scaled)

    for (int t0 = 0; t0 < TM1; t0 += 64) {
        float xvn = x[min(t0 + 64 + lane, TM1 - 1) * BATCH + b];
        const int nsteps = min(64, TM1 - t0);
        float outy = 0.f;

        for (int kk = 0; kk < nsteps; ++kk) {
            // tanh in r-form: t=exp2(z); r=rcp(t+1). (h = 1-2r implicit.)
            float t = __builtin_amdgcn_exp2f(z);
            float r = __builtin_amdgcn_rcpf(t + 1.f);

            // Off-chain prep for next step's z.
            const int nk = kk + 1;
            float xsrc = (nk == 64) ? xvn : xv;
            float xtn  = bcast(xsrc, nk & 63);
            float zbase = fmaf(xtn, w1xK, V);   // z' = zbase + R

            // Stage 1 (xor1, fused, packed) on r with -2-scaled weights.
            float rx = dppmov<0xB1>(r);         // quad_perm [1,0,3,2]
            v2f r2v = (v2f){r, r};
            v2f rx2 = (v2f){rx, rx};
            v2f u1p[4];
            #pragma unroll
            for (int m = 0; m < 4; ++m)
                u1p[m] = __builtin_elementwise_fma(rx2, wB2[m], r2v * wA2[m]);

            // Stage 2 (xor2 = quad_perm [2,3,0,1]).
            float u2[4];
            #pragma unroll
            for (int m = 0; m < 4; ++m)
                u2[m] = u1p[m].x + dppmov<0x4E>(u1p[m].y);

            // Stage 3 (xor7 = row_half_mirror).
            float u3a = u2[0] + dppmov<0x141>(u2[1]);
            float u3b = u2[2] + dppmov<0x141>(u2[3]);

            // Stage 4 (xor8 = row_ror:8).
            float Pb = u3a + dppmov<0x128>(u3b);

            // Cross-row combine: 3 INDEPENDENT DS ops, one latency (R6).
            int   Pi  = __builtin_bit_cast(int, Pb);
            float a16 = __builtin_bit_cast(float,
                        __builtin_amdgcn_ds_swizzle(Pi, 0x401F));       // ^16
            float a32 = __builtin_bit_cast(float,
                        __builtin_amdgcn_ds_bpermute(bp32, Pi));        // ^32
            float a48 = __builtin_bit_cast(float,
                        __builtin_amdgcn_ds_bpermute(bp48, Pi));        // ^48
            Pb = (Pb + a16) + (a32 + a48);
            // Lane holds Pb_{lane&15}; p_s = pconst_s + Pb_s.

            // y0 path: p0 = pconst0 + Pb0 (full magnitude), b20 at store.
            y0 += pconst0 + bcast(Pb, 0);
            outy = (kk == lane) ? y0 : outy;

            // R = C2 + sum_s Pb_s*w1yd[s] — packed combine: SGPR-broadcast
            // pairs into v_pk_fma_f32 (VOP3P, one 64-bit scalar operand);
            // 2 chains x depth 4, then pk_add + scalar add.
            v2f accA = __builtin_elementwise_fma(
                (v2f){bcast(Pb, 0), bcast(Pb, 1)}, w1yd2[0], (v2f){C2, 0.f});
            accA = __builtin_elementwise_fma(
                (v2f){bcast(Pb, 4), bcast(Pb, 5)}, w1yd2[2], accA);
            accA = __builtin_elementwise_fma(
                (v2f){bcast(Pb, 8), bcast(Pb, 9)}, w1yd2[4], accA);
            accA = __builtin_elementwise_fma(
                (v2f){bcast(Pb, 12), bcast(Pb, 13)}, w1yd2[6], accA);
            v2f accB = (v2f){bcast(Pb, 2), bcast(Pb, 3)} * w1yd2[1];
            accB = __builtin_elementwise_fma(
                (v2f){bcast(Pb, 6), bcast(Pb, 7)}, w1yd2[3], accB);
            accB = __builtin_elementwise_fma(
                (v2f){bcast(Pb, 10), bcast(Pb, 11)}, w1yd2[5], accB);
            accB = __builtin_elementwise_fma(
                (v2f){bcast(Pb, 14), bcast(Pb, 15)}, w1yd2[7], accB);
            v2f accS = accA + accB;
            float R = accS.x + accS.y;

            z = zbase + R;       // critical-path tail: single add
            V = V + R;           // off-chain, feeds next step's zbase
        }

        // Store: add back n*b2[0], one IEEE div, coalesced.
        if (lane < nsteps) {
            const int n = t0 + 1 + lane;
            out[n * BATCH + b] = fmaf((float)n, b20, outy) / SRATE;
        }
        xv = xvn;
    }
}

extern "C" void kernel_launch(void* const* d_in, const int* in_sizes, int n_in,
                              void* d_out, int out_size, void* d_ws, size_t ws_size,
                              hipStream_t stream) {
    const float* x  = (const float*)d_in[0];
    const float* W1 = (const float*)d_in[1];
    const float* b1 = (const float*)d_in[2];
    const float* W2 = (const float*)d_in[3];
    const float* b2 = (const float*)d_in[4];
    float* out = (float*)d_out;

    ScaledODENetFE_kernel<<<BATCH, 64, 0, stream>>>(x, W1, b1, W2, b2, out);
}

// Round 15
// 7527.615 us; speedup vs baseline: 1.0763x; 1.0763x over previous
//
#include <hip/hip_runtime.h>

// ScaledODENetFE: forward-Euler scan, T=44100, B=32, F=1, S=16, H=64.
// One wave per batch; lane k owns hidden unit k. Bound by a single wave's
// dependency chain + issue (44099 serial steps; tanh blocks time-parallel).
// R14 = R11 (best: 7.11 ms) + ONE bit-exact change: the inner loop's
// chunk-boundary select ((nk==64)?xvn:xv cndmask + nk&63) is removed by
// peeling the last iteration: steps 0..n-2 use bcast(xv,kk+1); the final
// step uses bcast(xvn,0). Identical values flow -> bit-identical trajectory.
// Combine stays R11's scalar readlane + 4-chain FMA: LDS broadcast (R7),
// DPP rotation (R9/R12), and VOP3P packing (R13) all regressed against it.
// BANNED: permlane16/32_swap (R4/R5 wrong data), LDS P-broadcast on-chain
// (R7), carry reconstruction by large-value cancellation (R10).

#define SRATE 44100.0f
#define T_TOTAL 44100
#define BATCH 32
#define HID 64
#define ST 16
#define KSCALE 2.8853900817779268f   // 2*log2(e)

typedef float v2f __attribute__((ext_vector_type(2)));

template <int CTRL>
__device__ __forceinline__ float dppmov(float x) {
    return __builtin_bit_cast(float,
        __builtin_amdgcn_update_dpp(0, __builtin_bit_cast(int, x),
                                    CTRL, 0xF, 0xF, false));
}

__device__ __forceinline__ float bcast(float v, int lane) {
    return __builtin_bit_cast(float,
        __builtin_amdgcn_readlane(__builtin_bit_cast(int, v), lane));
}

__device__ __forceinline__ int parity(int v) { return __builtin_popcount(v) & 1; }

__global__ __launch_bounds__(64, 1)
void ScaledODENetFE_kernel(const float* __restrict__ x,
                           const float* __restrict__ W1,
                           const float* __restrict__ b1,
                           const float* __restrict__ W2,
                           const float* __restrict__ b2v,
                           float* __restrict__ out) {
    const int b = blockIdx.x;      // batch element
    const int lane = threadIdx.x;  // hidden unit k
    const int TM1 = T_TOTAL - 1;   // 44099 scan steps

    // ---- one-time precompute (lane k) ----
    const float w1xK = W1[lane] * KSCALE;       // K-scaled x weight
    float w1yd[ST];                             // K * W1[1+s][lane] / sr
    #pragma unroll
    for (int s = 0; s < ST; ++s)
        w1yd[s] = (W1[(1 + s) * HID + lane] / SRATE) * KSCALE;

    // C2 = sum_s (b2[s] + pconst_s) * w1yd[s];  pconst_s = sum_k W2[k,s].
    float C2 = 0.f;
    #pragma unroll
    for (int s = 0; s < ST; ++s) C2 = fmaf(b2v[s], w1yd[s], C2);
    float pconst0 = 0.f;
    for (int s = 0; s < ST; ++s) {
        float pc = 0.f;
        for (int k = 0; k < HID; ++k) pc += W2[k * ST + s];
        C2 = fmaf(pc, w1yd[s], C2);
        if (s == 0) pconst0 = pc;
    }

    // Dual-basis lane phis for the permuted W2 layout (XOR gens 1,2,7,8),
    // weights pre-scaled by -2 (r-form: p = pconst - 2 * W2^T r).
    const int p1 = parity(lane & 5), p2 = parity(lane & 6);
    const int p3 = (lane >> 2) & 1, p4 = (lane >> 3) & 1;
    float wA[8], wB[8];
    #pragma unroll
    for (int j = 0; j < 8; ++j) {
        const int i = 2 * j;
        const int c1 = (i & 1) ^ p1;
        const int c2 = ((i >> 1) & 1) ^ p2;
        const int c3 = ((i >> 2) & 1) ^ p3;
        const int c4 = ((i >> 3) & 1) ^ p4;
        const int s = (c1 ? 1 : 0) ^ (c2 ? 2 : 0) ^ (c3 ? 7 : 0) ^ (c4 ? 8 : 0);
        wA[j] = -2.f * W2[lane * ST + s];
        wB[j] = -2.f * W2[(lane ^ 1) * ST + s];
    }
    v2f wA2[4], wB2[4];
    #pragma unroll
    for (int m = 0; m < 4; ++m) {
        wA2[m] = (v2f){wA[2 * m], wA[2 * m + 1]};
        wB2[m] = (v2f){wB[2 * m], wB[2 * m + 1]};
    }

    const int bp32 = ((lane ^ 32) & 63) << 2;   // ds_bpermute byte addrs
    const int bp48 = ((lane ^ 48) & 63) << 2;
    const float b20 = b2v[0];

    float V  = b1[lane] * KSCALE;               // K-scaled carry (y starts 0)
    float y0 = 0.f;

    if (lane == 0) out[b] = 0.f;                // row t=0 is zeros

    // Lane l holds x[(t0+l)*B + b]; prefetch one chunk ahead.
    float xv = x[min(lane, TM1 - 1) * BATCH + b];
    float z = fmaf(bcast(xv, 0), w1xK, V);      // z_0 (K-scaled)

    for (int t0 = 0; t0 < TM1; t0 += 64) {
        float xvn = x[min(t0 + 64 + lane, TM1 - 1) * BATCH + b];
        const int nsteps = min(64, TM1 - t0);
        float outy = 0.f;

        // One scan step; xtn = next step's input sample (wave-uniform).
        auto step = [&](int kk, float xtn) {
            // tanh in r-form: t=exp2(z); r=rcp(t+1). (h = 1-2r implicit;
            // saturation via inf/0 semantics — R8-validated.)
            float t = __builtin_amdgcn_exp2f(z);
            float r = __builtin_amdgcn_rcpf(t + 1.f);

            // Off-chain prep for next step's z.
            float zbase = fmaf(xtn, w1xK, V);   // z' = zbase + R

            // Stage 1 (xor1, fused, packed) on r with -2-scaled weights.
            float rx = dppmov<0xB1>(r);         // quad_perm [1,0,3,2]
            v2f r2v = (v2f){r, r};
            v2f rx2 = (v2f){rx, rx};
            v2f u1p[4];
            #pragma unroll
            for (int m = 0; m < 4; ++m)
                u1p[m] = __builtin_elementwise_fma(rx2, wB2[m], r2v * wA2[m]);

            // Stage 2 (xor2 = quad_perm [2,3,0,1]).
            float u2[4];
            #pragma unroll
            for (int m = 0; m < 4; ++m)
                u2[m] = u1p[m].x + dppmov<0x4E>(u1p[m].y);

            // Stage 3 (xor7 = row_half_mirror).
            float u3a = u2[0] + dppmov<0x141>(u2[1]);
            float u3b = u2[2] + dppmov<0x141>(u2[3]);

            // Stage 4 (xor8 = row_ror:8).
            float Pb = u3a + dppmov<0x128>(u3b);

            // Cross-row combine: 3 INDEPENDENT DS ops, one latency (R6).
            int   Pi  = __builtin_bit_cast(int, Pb);
            float a16 = __builtin_bit_cast(float,
                        __builtin_amdgcn_ds_swizzle(Pi, 0x401F));       // ^16
            float a32 = __builtin_bit_cast(float,
                        __builtin_amdgcn_ds_bpermute(bp32, Pi));        // ^32
            float a48 = __builtin_bit_cast(float,
                        __builtin_amdgcn_ds_bpermute(bp48, Pi));        // ^48
            Pb = (Pb + a16) + (a32 + a48);
            // Lane holds Pb_{lane&15}; p_s = pconst_s + Pb_s.

            // y0 path: p0 = pconst0 + Pb0 (full magnitude), b20 at store.
            y0 += pconst0 + bcast(Pb, 0);
            outy = (kk == lane) ? y0 : outy;

            // R = C2 + sum_s Pb_s*w1yd[s]: scalar readlane + 4-chain FMA
            // (empirical optimum — R7/R9/R12/R13 alternatives all regressed).
            float r0 = fmaf(bcast(Pb, 0), w1yd[0], C2);
            float r1 = bcast(Pb, 4)  * w1yd[4];
            float r2 = bcast(Pb, 8)  * w1yd[8];
            float r3 = bcast(Pb, 12) * w1yd[12];
            #pragma unroll
            for (int q = 1; q < 4; ++q) {
                r0 = fmaf(bcast(Pb, q),      w1yd[q],      r0);
                r1 = fmaf(bcast(Pb, 4 + q),  w1yd[4 + q],  r1);
                r2 = fmaf(bcast(Pb, 8 + q),  w1yd[8 + q],  r2);
                r3 = fmaf(bcast(Pb, 12 + q), w1yd[12 + q], r3);
            }
            float R = (r0 + r1) + (r2 + r3);

            z = zbase + R;       // critical-path tail: single add
            V = V + R;           // off-chain, feeds next step's zbase
        };

        // Peeled loop: no boundary select inside the hot body (bit-exact).
        for (int kk = 0; kk + 1 < nsteps; ++kk)
            step(kk, bcast(xv, kk + 1));
        step(nsteps - 1, bcast(xvn, 0));

        // Store: add back n*b2[0], one IEEE div, coalesced.
        if (lane < nsteps) {
            const int n = t0 + 1 + lane;
            out[n * BATCH + b] = fmaf((float)n, b20, outy) / SRATE;
        }
        xv = xvn;
    }
}

extern "C" void kernel_launch(void* const* d_in, const int* in_sizes, int n_in,
                              void* d_out, int out_size, void* d_ws, size_t ws_size,
                              hipStream_t stream) {
    const float* x  = (const float*)d_in[0];
    const float* W1 = (const float*)d_in[1];
    const float* b1 = (const float*)d_in[2];
    const float* W2 = (const float*)d_in[3];
    const float* b2 = (const float*)d_in[4];
    float* out = (float*)d_out;

    ScaledODENetFE_kernel<<<BATCH, 64, 0, stream>>>(x, W1, b1, W2, b2, out);
}

// Round 16
// 7138.831 us; speedup vs baseline: 1.1349x; 1.0545x over previous
//
#include <hip/hip_runtime.h>

// ScaledODENetFE: forward-Euler scan, T=44100, B=32, F=1, S=16, H=64.
// One wave per batch; lane k owns hidden unit k. Chain-latency bound.
// R15 = R11 VERBATIM (empirical optimum, 7.11 ms). Every neighborhood
// restructure regressed: LDS P-broadcast (R7 +0.9ms), DPP rotation combine
// (R9/R12 +0.6/+0.8ms), VOP3P packed combine (R13 +0.9ms), loop peel
// (R14 +0.4ms), carry reconstruction by cancellation (R10 incorrect),
// permlane16/32_swap (R4/R5 wrong data on HW).
// Structure: r-form butterfly (rcp of exp2, -2-scaled W2), K-fold carry,
// xor-basis {1,2,7,8} DPP reduce-scatter + 3-parallel-DS cross-row,
// scalar readlane + 4-chain FMA combine, R materialized at own scale,
// z = zbase + R on-chain / V += R off-chain, b2[0] folded to store.

#define SRATE 44100.0f
#define T_TOTAL 44100
#define BATCH 32
#define HID 64
#define ST 16
#define KSCALE 2.8853900817779268f   // 2*log2(e)

typedef float v2f __attribute__((ext_vector_type(2)));

template <int CTRL>
__device__ __forceinline__ float dppmov(float x) {
    return __builtin_bit_cast(float,
        __builtin_amdgcn_update_dpp(0, __builtin_bit_cast(int, x),
                                    CTRL, 0xF, 0xF, false));
}

__device__ __forceinline__ float bcast(float v, int lane) {
    return __builtin_bit_cast(float,
        __builtin_amdgcn_readlane(__builtin_bit_cast(int, v), lane));
}

__device__ __forceinline__ int parity(int v) { return __builtin_popcount(v) & 1; }

__global__ __launch_bounds__(64, 1)
void ScaledODENetFE_kernel(const float* __restrict__ x,
                           const float* __restrict__ W1,
                           const float* __restrict__ b1,
                           const float* __restrict__ W2,
                           const float* __restrict__ b2v,
                           float* __restrict__ out) {
    const int b = blockIdx.x;      // batch element
    const int lane = threadIdx.x;  // hidden unit k
    const int TM1 = T_TOTAL - 1;   // 44099 scan steps

    // ---- one-time precompute (lane k) ----
    const float w1xK = W1[lane] * KSCALE;       // K-scaled x weight
    float w1yd[ST];                             // K * W1[1+s][lane] / sr
    #pragma unroll
    for (int s = 0; s < ST; ++s)
        w1yd[s] = (W1[(1 + s) * HID + lane] / SRATE) * KSCALE;

    // C2 = sum_s (b2[s] + pconst_s) * w1yd[s];  pconst_s = sum_k W2[k,s].
    float C2 = 0.f;
    #pragma unroll
    for (int s = 0; s < ST; ++s) C2 = fmaf(b2v[s], w1yd[s], C2);
    float pconst0 = 0.f;
    for (int s = 0; s < ST; ++s) {
        float pc = 0.f;
        for (int k = 0; k < HID; ++k) pc += W2[k * ST + s];
        C2 = fmaf(pc, w1yd[s], C2);
        if (s == 0) pconst0 = pc;
    }

    // Dual-basis lane phis for the permuted W2 layout (XOR gens 1,2,7,8),
    // weights pre-scaled by -2 (r-form: p = pconst - 2 * W2^T r).
    const int p1 = parity(lane & 5), p2 = parity(lane & 6);
    const int p3 = (lane >> 2) & 1, p4 = (lane >> 3) & 1;
    float wA[8], wB[8];
    #pragma unroll
    for (int j = 0; j < 8; ++j) {
        const int i = 2 * j;
        const int c1 = (i & 1) ^ p1;
        const int c2 = ((i >> 1) & 1) ^ p2;
        const int c3 = ((i >> 2) & 1) ^ p3;
        const int c4 = ((i >> 3) & 1) ^ p4;
        const int s = (c1 ? 1 : 0) ^ (c2 ? 2 : 0) ^ (c3 ? 7 : 0) ^ (c4 ? 8 : 0);
        wA[j] = -2.f * W2[lane * ST + s];
        wB[j] = -2.f * W2[(lane ^ 1) * ST + s];
    }
    v2f wA2[4], wB2[4];
    #pragma unroll
    for (int m = 0; m < 4; ++m) {
        wA2[m] = (v2f){wA[2 * m], wA[2 * m + 1]};
        wB2[m] = (v2f){wB[2 * m], wB[2 * m + 1]};
    }

    const int bp32 = ((lane ^ 32) & 63) << 2;   // ds_bpermute byte addrs
    const int bp48 = ((lane ^ 48) & 63) << 2;
    const float b20 = b2v[0];

    float V  = b1[lane] * KSCALE;               // K-scaled carry (y starts 0)
    float y0 = 0.f;

    if (lane == 0) out[b] = 0.f;                // row t=0 is zeros

    // Lane l holds x[(t0+l)*B + b]; prefetch one chunk ahead.
    float xv = x[min(lane, TM1 - 1) * BATCH + b];
    float z = fmaf(bcast(xv, 0), w1xK, V);      // z_0 (K-scaled)

    for (int t0 = 0; t0 < TM1; t0 += 64) {
        float xvn = x[min(t0 + 64 + lane, TM1 - 1) * BATCH + b];
        const int nsteps = min(64, TM1 - t0);
        float outy = 0.f;

        for (int kk = 0; kk < nsteps; ++kk) {
            // tanh in r-form: t=exp2(z); r=rcp(t+1). (h = 1-2r implicit;
            // saturation via inf/0 semantics — R8-validated.)
            float t = __builtin_amdgcn_exp2f(z);
            float r = __builtin_amdgcn_rcpf(t + 1.f);

            // Off-chain prep for next step's z.
            const int nk = kk + 1;
            float xsrc = (nk == 64) ? xvn : xv;
            float xtn  = bcast(xsrc, nk & 63);
            float zbase = fmaf(xtn, w1xK, V);   // z' = zbase + R

            // Stage 1 (xor1, fused, packed) on r with -2-scaled weights.
            float rx = dppmov<0xB1>(r);         // quad_perm [1,0,3,2]
            v2f r2v = (v2f){r, r};
            v2f rx2 = (v2f){rx, rx};
            v2f u1p[4];
            #pragma unroll
            for (int m = 0; m < 4; ++m)
                u1p[m] = __builtin_elementwise_fma(rx2, wB2[m], r2v * wA2[m]);

            // Stage 2 (xor2 = quad_perm [2,3,0,1]).
            float u2[4];
            #pragma unroll
            for (int m = 0; m < 4; ++m)
                u2[m] = u1p[m].x + dppmov<0x4E>(u1p[m].y);

            // Stage 3 (xor7 = row_half_mirror).
            float u3a = u2[0] + dppmov<0x141>(u2[1]);
            float u3b = u2[2] + dppmov<0x141>(u2[3]);

            // Stage 4 (xor8 = row_ror:8).
            float Pb = u3a + dppmov<0x128>(u3b);

            // Cross-row combine: 3 INDEPENDENT DS ops, one latency (R6).
            int   Pi  = __builtin_bit_cast(int, Pb);
            float a16 = __builtin_bit_cast(float,
                        __builtin_amdgcn_ds_swizzle(Pi, 0x401F));       // ^16
            float a32 = __builtin_bit_cast(float,
                        __builtin_amdgcn_ds_bpermute(bp32, Pi));        // ^32
            float a48 = __builtin_bit_cast(float,
                        __builtin_amdgcn_ds_bpermute(bp48, Pi));        // ^48
            Pb = (Pb + a16) + (a32 + a48);
            // Lane holds Pb_{lane&15}; p_s = pconst_s + Pb_s.

            // y0 path: p0 = pconst0 + Pb0 (full magnitude), b20 at store.
            y0 += pconst0 + bcast(Pb, 0);
            outy = (kk == lane) ? y0 : outy;

            // R = C2 + sum_s Pb_s*w1yd[s]: 4 chains, C2 seeded; R
            // materialized at its own scale (R10's z-seeded form banned).
            float r0 = fmaf(bcast(Pb, 0), w1yd[0], C2);
            float r1 = bcast(Pb, 4)  * w1yd[4];
            float r2 = bcast(Pb, 8)  * w1yd[8];
            float r3 = bcast(Pb, 12) * w1yd[12];
            #pragma unroll
            for (int q = 1; q < 4; ++q) {
                r0 = fmaf(bcast(Pb, q),      w1yd[q],      r0);
                r1 = fmaf(bcast(Pb, 4 + q),  w1yd[4 + q],  r1);
                r2 = fmaf(bcast(Pb, 8 + q),  w1yd[8 + q],  r2);
                r3 = fmaf(bcast(Pb, 12 + q), w1yd[12 + q], r3);
            }
            float R = (r0 + r1) + (r2 + r3);

            z = zbase + R;       // critical-path tail: single add
            V = V + R;           // off-chain, feeds next step's zbase
        }

        // Store: add back n*b2[0], one IEEE div, coalesced.
        if (lane < nsteps) {
            const int n = t0 + 1 + lane;
            out[n * BATCH + b] = fmaf((float)n, b20, outy) / SRATE;
        }
        xv = xvn;
    }
}

extern "C" void kernel_launch(void* const* d_in, const int* in_sizes, int n_in,
                              void* d_out, int out_size, void* d_ws, size_t ws_size,
                              hipStream_t stream) {
    const float* x  = (const float*)d_in[0];
    const float* W1 = (const float*)d_in[1];
    const float* b1 = (const float*)d_in[2];
    const float* W2 = (const float*)d_in[3];
    const float* b2 = (const float*)d_in[4];
    float* out = (float*)d_out;

    ScaledODENetFE_kernel<<<BATCH, 64, 0, stream>>>(x, W1, b1, W2, b2, out);
}